// Round 2
// baseline (1905.909 us; speedup 1.0000x reference)
//
#include <hip/hip_runtime.h>
#include <hip/hip_bf16.h>
#include <hip/hip_fp16.h>
#include <math.h>

constexpr int N_NODES = 50000;
constexpr int N_EDGES = 850000;
constexpr int HDIM = 128;   // H*D
constexpr int AGG_BLOCKS = N_NODES / 8;  // 6250

typedef _Float16 f16x8 __attribute__((ext_vector_type(8)));
typedef float f32x4 __attribute__((ext_vector_type(4)));

// ---------------- CSR build: two-phase bucket sort ----------------
constexpr int NB2 = 128;                                // buckets
constexpr int RANGE2 = (N_NODES + NB2 - 1) / NB2;       // 391 nodes/bucket
constexpr int CAP = 8192;                               // bucket capacity (avg 6641)
constexpr int CHUNK = 8192;                             // edges per phase-A block
constexpr int GA = (N_EDGES + CHUNK - 1) / CHUNK;       // 104 blocks

__global__ void k_partA(const int* __restrict__ src, const int* __restrict__ dst,
                        int* __restrict__ g_cursor, unsigned* __restrict__ bucket) {
    __shared__ int hist[NB2];
    int tid = threadIdx.x;
    int e0 = blockIdx.x * CHUNK;
    int e1 = min(e0 + CHUNK, N_EDGES);
    if (tid < NB2) hist[tid] = 0;
    __syncthreads();
    for (int i = e0 + tid; i < e1; i += 1024) {
        int d = dst[i];
        atomicAdd(&hist[d / RANGE2], 1);
    }
    __syncthreads();
    int base = 0;
    if (tid < NB2) base = atomicAdd(&g_cursor[tid], hist[tid]);
    __syncthreads();
    if (tid < NB2) hist[tid] = base;
    __syncthreads();
    for (int i = e0 + tid; i < e1; i += 1024) {
        int d = dst[i];
        int s = src[i];
        int b = d / RANGE2;
        int p = atomicAdd(&hist[b], 1);
        bucket[b * CAP + p] = (unsigned)s | ((unsigned)(d - b * RANGE2) << 16);
    }
}

__global__ void k_partB(const unsigned* __restrict__ bucket, const int* __restrict__ cnts,
                        int* __restrict__ rowstart, int* __restrict__ esrc) {
    __shared__ int cnt_s[NB2];
    __shared__ int hist[RANGE2];
    __shared__ int lcur[RANGE2];
    __shared__ int wsum[7];
    int b = blockIdx.x, tid = threadIdx.x;
    int lo = b * RANGE2;
    int myCount = cnts[b];
    if (tid < NB2) cnt_s[tid] = cnts[tid];
    __syncthreads();
    for (int off = 1; off < NB2; off <<= 1) {
        int t = (tid < NB2 && tid >= off) ? cnt_s[tid - off] : 0;
        __syncthreads();
        if (tid < NB2) cnt_s[tid] += t;
        __syncthreads();
    }
    int base = cnt_s[b] - myCount;
    for (int j = tid; j < RANGE2; j += 1024) hist[j] = 0;
    __syncthreads();
    const unsigned* my = bucket + (size_t)b * CAP;
    for (int i = tid; i < myCount; i += 1024) atomicAdd(&hist[my[i] >> 16], 1);
    __syncthreads();
    int v = 0;
    if (tid < 448) v = (tid < RANGE2) ? hist[tid] : 0;
    int inc = v;
    int lane = tid & 63;
#pragma unroll
    for (int off = 1; off < 64; off <<= 1) {
        int t = __shfl_up(inc, off, 64);
        if (lane >= off) inc += t;
    }
    if (tid < 448 && lane == 63) wsum[tid >> 6] = inc;
    __syncthreads();
    if (tid < RANGE2) {
        int woff = 0;
        for (int w = 0; w < (tid >> 6); w++) woff += wsum[w];
        int excl = woff + inc - v;
        lcur[tid] = excl;
        int node = lo + tid;
        if (node < N_NODES) rowstart[node] = base + excl;
    }
    if (b == 0 && tid == 0) rowstart[N_NODES] = N_EDGES;
    __syncthreads();
    for (int i = tid; i < myCount; i += 1024) {
        unsigned p = my[i];
        int pos = atomicAdd(&lcur[p >> 16], 1);
        esrc[base + pos] = (int)(p & 0xFFFFu);
    }
}

// ---------------- W pre-pack into MFMA B-fragment layout + workspace zeroing ----------------
// For (L, ct, kc, lane): 8 halves  W[kc*32 + (lane>>4)*8 + j][ct*16 + (lane&15)]
// stored at wpk[L*16384 + ((ct*4+kc)*64 + lane)*8 + j]
// Also zeroes: bn_part (3*16384 floats), bn_cnt (3 ints), g_cursor (128 ints).
__global__ void k_wpack(const float* __restrict__ W0, const float* __restrict__ W1,
                        const float* __restrict__ W2, __half* __restrict__ wpk,
                        float* __restrict__ bn_part, int* __restrict__ bn_cnt,
                        int* __restrict__ g_cursor) {
    int gid = blockIdx.x * 256 + threadIdx.x;  // 24 * 256 = 6144
    {
        int z0 = gid * 8;
        if (z0 < 3 * 16384) {
            float4 z = make_float4(0.f, 0.f, 0.f, 0.f);
            *reinterpret_cast<float4*>(&bn_part[z0]) = z;
            *reinterpret_cast<float4*>(&bn_part[z0 + 4]) = z;
        }
        if (gid < 3) bn_cnt[gid] = 0;
        if (gid < NB2) g_cursor[gid] = 0;
    }
    if (gid >= 3 * 2048) return;
    int L = gid >> 11;
    int rem = gid & 2047;
    int ct = rem >> 8;
    int kc = (rem >> 6) & 3;
    int l = rem & 63;
    const float* W = (L == 0) ? W0 : ((L == 1) ? W1 : W2);
    int c = ct * 16 + (l & 15);
    int k0 = kc * 32 + (l >> 4) * 8;
    __half tmp[8];
#pragma unroll
    for (int j = 0; j < 8; j++) tmp[j] = __float2half(W[(k0 + j) * HDIM + c]);
    *reinterpret_cast<float4*>(&wpk[((size_t)L << 14) + ((size_t)(ct * 4 + kc) * 64 + l) * 8]) =
        *reinterpret_cast<float4*>(tmp);
}

// ---------------- GEMM v5: MFMA 16x16x32_f16 ----------------
__global__ void k_gemm5(const __half* __restrict__ h, const int* __restrict__ xidx,
                        const float* __restrict__ embed, const f16x8* __restrict__ wB,
                        __half* __restrict__ feat_h, const float* __restrict__ bnsc,
                        const float* __restrict__ bnsh, const float* __restrict__ al,
                        const float* __restrict__ ar, float* __restrict__ el,
                        float* __restrict__ er, int mode) {
    __shared__ __half sf[4][16][136];  // per-wave 16x128 fp16 tile (+8 pad), 17.4 KB
    int tid = threadIdx.x;
    int w = tid >> 6, lane = tid & 63;
    int r = lane & 15, kg = lane >> 4;
    int wbase = blockIdx.x * 64 + w * 16;
    int n = wbase + r;
    bool ok = n < N_NODES;

    // ---- A fragments: aF[kc][j] = act[n][kc*32 + kg*8 + j] ----
    f16x8 aF[4];
#pragma unroll
    for (int kc = 0; kc < 4; kc++)
#pragma unroll
        for (int j = 0; j < 8; j++) aF[kc][j] = (_Float16)0.f;
    if (ok) {
        if (mode == 0) {
            int xi = xidx[n];
            const float* ep = embed + (size_t)xi * HDIM;
#pragma unroll
            for (int kc = 0; kc < 4; kc++) {
                int c0 = kc * 32 + kg * 8;
                float4 e0 = *reinterpret_cast<const float4*>(ep + c0);
                float4 e1 = *reinterpret_cast<const float4*>(ep + c0 + 4);
                aF[kc][0] = (_Float16)e0.x; aF[kc][1] = (_Float16)e0.y;
                aF[kc][2] = (_Float16)e0.z; aF[kc][3] = (_Float16)e0.w;
                aF[kc][4] = (_Float16)e1.x; aF[kc][5] = (_Float16)e1.y;
                aF[kc][6] = (_Float16)e1.z; aF[kc][7] = (_Float16)e1.w;
            }
        } else {
            const __half* hp = h + (size_t)n * HDIM;
#pragma unroll
            for (int kc = 0; kc < 4; kc++) {
                int c0 = kc * 32 + kg * 8;
                float4 raw = *reinterpret_cast<const float4*>(hp + c0);
                const __half2* u = reinterpret_cast<const __half2*>(&raw);
                float4 sc0 = *reinterpret_cast<const float4*>(&bnsc[c0]);
                float4 sc1 = *reinterpret_cast<const float4*>(&bnsc[c0 + 4]);
                float4 sh0 = *reinterpret_cast<const float4*>(&bnsh[c0]);
                float4 sh1 = *reinterpret_cast<const float4*>(&bnsh[c0 + 4]);
                float scv[8] = {sc0.x, sc0.y, sc0.z, sc0.w, sc1.x, sc1.y, sc1.z, sc1.w};
                float shv[8] = {sh0.x, sh0.y, sh0.z, sh0.w, sh1.x, sh1.y, sh1.z, sh1.w};
                float vv[8];
#pragma unroll
                for (int t = 0; t < 4; t++) {
                    vv[2 * t] = __half2float(__low2half(u[t]));
                    vv[2 * t + 1] = __half2float(__high2half(u[t]));
                }
#pragma unroll
                for (int j = 0; j < 8; j++) {
                    float t = vv[j] * scv[j] + shv[j];
                    t = (t > 0.f) ? t : expm1f(t);
                    aF[kc][j] = (_Float16)t;
                }
            }
        }
    }

    // ---- MFMA main: acc[ct] over 4 K-chunks ----
    f32x4 acc[8] = {};
#pragma unroll
    for (int kc = 0; kc < 4; kc++) {
#pragma unroll
        for (int ct = 0; ct < 8; ct++) {
            f16x8 bF = wB[(ct * 4 + kc) * 64 + lane];
            acc[ct] = __builtin_amdgcn_mfma_f32_16x16x32_f16(aF[kc], bF, acc[ct], 0, 0, 0);
        }
    }

    // ---- feat store: C/D layout col=lane&15 (within ct), row=kg*4+reg ----
#pragma unroll
    for (int ct = 0; ct < 8; ct++)
#pragma unroll
        for (int reg = 0; reg < 4; reg++)
            sf[w][kg * 4 + reg][ct * 16 + r] = __float2half(acc[ct][reg]);
    __syncthreads();
#pragma unroll
    for (int q = 0; q < 4; q++) {
        int row = q * 4 + kg;
        int n2 = wbase + row;
        if (n2 < N_NODES) {
            float4 v = *reinterpret_cast<const float4*>(&sf[w][row][r * 8]);
            *reinterpret_cast<float4*>(&feat_h[(size_t)n2 * HDIM + r * 8]) = v;
        }
    }

    // ---- fused el/er: head hd covers ct=2hd, 2hd+1; reduce over 16 lanes (cols) ----
    float alq[8], arq[8];
#pragma unroll
    for (int ct = 0; ct < 8; ct++) {
        alq[ct] = al[ct * 16 + r];
        arq[ct] = ar[ct * 16 + r];
    }
#pragma unroll
    for (int hd = 0; hd < 4; hd++) {
        float pl[4], pr[4];
#pragma unroll
        for (int reg = 0; reg < 4; reg++) {
            pl[reg] = acc[2 * hd][reg] * alq[2 * hd] + acc[2 * hd + 1][reg] * alq[2 * hd + 1];
            pr[reg] = acc[2 * hd][reg] * arq[2 * hd] + acc[2 * hd + 1][reg] * arq[2 * hd + 1];
        }
#pragma unroll
        for (int off = 1; off < 16; off <<= 1)
#pragma unroll
            for (int reg = 0; reg < 4; reg++) {
                pl[reg] += __shfl_xor(pl[reg], off, 64);
                pr[reg] += __shfl_xor(pr[reg], off, 64);
            }
        if (r == 0) {
#pragma unroll
            for (int reg = 0; reg < 4; reg++) {
                int n2 = wbase + kg * 4 + reg;
                if (n2 < N_NODES) {
                    el[n2 * 4 + hd] = pl[reg];
                    er[n2 * 4 + hd] = pr[reg];
                }
            }
        }
    }
}

// ---------------- aggregation v8: v7 + fused BatchNorm stats (last-block pattern) ----------------
__global__ void k_agg8(const __half* __restrict__ feat_h, const float* __restrict__ el,
                       const float* __restrict__ er, const int* __restrict__ rowstart,
                       const int* __restrict__ esrc, const float* __restrict__ snorm_n,
                       __half* __restrict__ h, float* __restrict__ bnsc,
                       float* __restrict__ bnsh, const float* __restrict__ gamma,
                       const float* __restrict__ beta, float* __restrict__ bn_part,
                       int* __restrict__ bn_cnt, int layer) {
    __shared__ __align__(16) int2 lds[4][2][2][32][4];  // [wave][h2][buf][slot][head], 16 KB
    __shared__ int isLast;
    int tid = threadIdx.x;
    int wave = tid >> 6, lane = tid & 63;
    int h2 = lane >> 5, hl = lane & 31;
    int dp = hl & 15, epair = hl >> 4, head = dp >> 2;
    int n = blockIdx.x * 8 + wave * 2 + h2;   // 6250 blocks * 8 = 50000 exactly
    int e0 = rowstart[n];
    int deg = rowstart[n + 1] - e0;           // >= 1 (self loops)
    int dmax = max(deg, __shfl_xor(deg, 32, 64));
    float4 er4 = *(const float4*)&er[n * 4];
    const float4* fp = reinterpret_cast<const float4*>(feat_h);
    float s = 0.f;
    float a[8] = {};
    int nch = (dmax + 31) >> 5;

    int idx0 = e0 + min(hl, deg - 1);
    int sidx_p = esrc[idx0];
    float4 el_p = *(const float4*)&el[sidx_p * 4];
    bool val_p = hl < deg;

    for (int c = 0; c < nch; c++) {
        float w0 = 0.f, w1 = 0.f, w2 = 0.f, w3 = 0.f;
        int sv = sidx_p;
        if (val_p) {
            float ex = el_p.x + er4.x, ey = el_p.y + er4.y;
            float ez = el_p.z + er4.z, ew = el_p.w + er4.w;
            ex = fmaxf(ex, 0.f) + 0.2f * fminf(ex, 0.f);
            ey = fmaxf(ey, 0.f) + 0.2f * fminf(ey, 0.f);
            ez = fmaxf(ez, 0.f) + 0.2f * fminf(ez, 0.f);
            ew = fmaxf(ew, 0.f) + 0.2f * fminf(ew, 0.f);
            w0 = __expf(ex); w1 = __expf(ey); w2 = __expf(ez); w3 = __expf(ew);
        }
        int4* wp = reinterpret_cast<int4*>(&lds[wave][h2][c & 1][hl][0]);
        wp[0] = make_int4(sv, __float_as_int(w0), sv, __float_as_int(w1));
        wp[1] = make_int4(sv, __float_as_int(w2), sv, __float_as_int(w3));
        if (c + 1 < nch) {
            int slot = (c + 1) * 32 + hl;
            int idx = e0 + min(slot, deg - 1);
            sidx_p = esrc[idx];
            el_p = *(const float4*)&el[sidx_p * 4];
            val_p = slot < deg;
        }
        int cnt = min(32, dmax - c * 32);
        int iters = (cnt + 1) >> 1;
#pragma unroll 2
        for (int j = 0; j < iters; j++) {
            int2 rec = lds[wave][h2][c & 1][j * 2 + epair][head];
            float w = __int_as_float(rec.y);
            float4 fv = fp[(size_t)rec.x * 16 + dp];
            __half2 p0 = *(__half2*)&fv.x, p1 = *(__half2*)&fv.y;
            __half2 p2 = *(__half2*)&fv.z, p3 = *(__half2*)&fv.w;
            a[0] = fmaf(__half2float(__low2half(p0)), w, a[0]);
            a[1] = fmaf(__half2float(__high2half(p0)), w, a[1]);
            a[2] = fmaf(__half2float(__low2half(p1)), w, a[2]);
            a[3] = fmaf(__half2float(__high2half(p1)), w, a[3]);
            a[4] = fmaf(__half2float(__low2half(p2)), w, a[4]);
            a[5] = fmaf(__half2float(__high2half(p2)), w, a[5]);
            a[6] = fmaf(__half2float(__low2half(p3)), w, a[6]);
            a[7] = fmaf(__half2float(__high2half(p3)), w, a[7]);
            s += w;
        }
    }
#pragma unroll
    for (int k = 0; k < 8; k++) a[k] += __shfl_xor(a[k], 16, 64);
    s += __shfl_xor(s, 16, 64);
    float r[8] = {};
    if (epair == 0) {
        float inv = 1.f / s;
        int d0 = dp * 8;
#pragma unroll
        for (int k = 0; k < 8; k++) r[k] = a[k] * inv;
        if (layer > 0) {
            float4 hraw = *reinterpret_cast<const float4*>(&h[(size_t)n * HDIM + d0]);
            __half2 q0 = *(__half2*)&hraw.x, q1 = *(__half2*)&hraw.y;
            __half2 q2 = *(__half2*)&hraw.z, q3 = *(__half2*)&hraw.w;
            float hv[8] = {__half2float(__low2half(q0)), __half2float(__high2half(q0)),
                           __half2float(__low2half(q1)), __half2float(__high2half(q1)),
                           __half2float(__low2half(q2)), __half2float(__high2half(q2)),
                           __half2float(__low2half(q3)), __half2float(__high2half(q3))};
            float4 sc0 = *reinterpret_cast<const float4*>(&bnsc[d0]);
            float4 sc1 = *reinterpret_cast<const float4*>(&bnsc[d0 + 4]);
            float4 sh0 = *reinterpret_cast<const float4*>(&bnsh[d0]);
            float4 sh1 = *reinterpret_cast<const float4*>(&bnsh[d0 + 4]);
            float scv[8] = {sc0.x, sc0.y, sc0.z, sc0.w, sc1.x, sc1.y, sc1.z, sc1.w};
            float shv[8] = {sh0.x, sh0.y, sh0.z, sh0.w, sh1.x, sh1.y, sh1.z, sh1.w};
#pragma unroll
            for (int k = 0; k < 8; k++) {
                float t = hv[k] * scv[k] + shv[k];
                t = (t > 0.f) ? t : expm1f(t);
                r[k] += t;
                r[k] = (r[k] > 0.f) ? r[k] : expm1f(r[k]);
            }
        }
        float sn = snorm_n[n];
#pragma unroll
        for (int k = 0; k < 8; k++) r[k] *= sn;
        float4 outv;
        *(__half2*)&outv.x = __floats2half2_rn(r[0], r[1]);
        *(__half2*)&outv.y = __floats2half2_rn(r[2], r[3]);
        *(__half2*)&outv.z = __floats2half2_rn(r[4], r[5]);
        *(__half2*)&outv.w = __floats2half2_rn(r[6], r[7]);
        *reinterpret_cast<float4*>(&h[(size_t)n * HDIM + d0]) = outv;
    }

    // ---- fused BN stats: per-block reduce (LDS alias) + 64-bucket global partials ----
    float* bsum = reinterpret_cast<float*>(lds);   // 2048 floats used (of 4096)
    __syncthreads();          // all waves done with their lds hot-loop regions
    if (epair == 0) {
        int n8 = wave * 2 + h2;
        int cbase = n8 * 128 + dp * 8;
#pragma unroll
        for (int k = 0; k < 8; k++) {
            bsum[cbase + k] = r[k];
            bsum[1024 + cbase + k] = r[k] * r[k];
        }
    }
    __syncthreads();
    {
        int c = tid & 127, which = tid >> 7;   // which: 0=sum, 1=sumsq
        float v = 0.f;
#pragma unroll
        for (int n8 = 0; n8 < 8; n8++) v += bsum[which * 1024 + n8 * 128 + c];
        atomicAdd(&bn_part[(blockIdx.x & 63) * 256 + which * 128 + c], v);
    }
    __threadfence();
    __syncthreads();
    if (tid == 0) isLast = (atomicAdd(bn_cnt, 1) == AGG_BLOCKS - 1);
    __syncthreads();
    if (isLast) {
        __threadfence();
        int c = tid & 127, which = tid >> 7;
        float t0 = 0.f, t1 = 0.f, t2 = 0.f, t3 = 0.f;
#pragma unroll
        for (int b = 0; b < 16; b++) {
            t0 += __hip_atomic_load(&bn_part[(4 * b + 0) * 256 + which * 128 + c],
                                    __ATOMIC_RELAXED, __HIP_MEMORY_SCOPE_AGENT);
            t1 += __hip_atomic_load(&bn_part[(4 * b + 1) * 256 + which * 128 + c],
                                    __ATOMIC_RELAXED, __HIP_MEMORY_SCOPE_AGENT);
            t2 += __hip_atomic_load(&bn_part[(4 * b + 2) * 256 + which * 128 + c],
                                    __ATOMIC_RELAXED, __HIP_MEMORY_SCOPE_AGENT);
            t3 += __hip_atomic_load(&bn_part[(4 * b + 3) * 256 + which * 128 + c],
                                    __ATOMIC_RELAXED, __HIP_MEMORY_SCOPE_AGENT);
        }
        bsum[tid] = (t0 + t1) + (t2 + t3);
        __syncthreads();
        if (tid < 128) {
            float mu = bsum[tid] * (1.f / N_NODES);
            float var = bsum[128 + tid] * (1.f / N_NODES) - mu * mu;
            float sc = gamma[tid] * rsqrtf(var + 1e-5f);
            bnsc[tid] = sc;
            bnsh[tid] = beta[tid] - mu * sc;
        }
    }
}

// ---------------- classifier (h fp16) ----------------
__global__ void k_classifier(const __half* __restrict__ h, const float* __restrict__ W1,
                             const float* __restrict__ b1, const float* __restrict__ W2,
                             const float* __restrict__ b2, const float* __restrict__ bnsc,
                             const float* __restrict__ bnsh, float* __restrict__ out) {
    __shared__ float hs[16][128];
    int tid = threadIdx.x;
    int nbase = blockIdx.x * 16;
    for (int i = tid; i < 16 * 128; i += 256) {
        int r = i >> 7, c = i & 127;
        int n = nbase + r;
        float v = 0.f;
        if (n < N_NODES) {
            v = __half2float(h[(size_t)n * HDIM + c]) * bnsc[c] + bnsh[c];
            v = (v > 0.f) ? v : expm1f(v);
        }
        hs[r][c] = v;
    }
    __syncthreads();
    int j = tid & 63;
    int g = tid >> 6;
    float bj = b1[j];
    float acc[4] = {bj, bj, bj, bj};
    for (int k = 0; k < 128; k++) {
        float w = W1[k * 64 + j];
#pragma unroll
        for (int i = 0; i < 4; i++) acc[i] += hs[g * 4 + i][k] * w;
    }
    float w20 = W2[j * 2], w21 = W2[j * 2 + 1];
    float res[8];
#pragma unroll
    for (int i = 0; i < 4; i++) {
        float hid = fmaxf(acc[i], 0.f);
        res[2 * i] = hid * w20;
        res[2 * i + 1] = hid * w21;
    }
#pragma unroll
    for (int off = 1; off < 64; off <<= 1)
#pragma unroll
        for (int i = 0; i < 8; i++) res[i] += __shfl_xor(res[i], off, 64);
    if (j < 8) {
        int n = nbase + g * 4 + (j >> 1);
        if (n < N_NODES) out[n * 2 + (j & 1)] = res[j] + b2[j & 1];
    }
}

// ----------------------------------------------------------------
extern "C" void kernel_launch(void* const* d_in, const int* in_sizes, int n_in,
                              void* d_out, int out_size, void* d_ws, size_t ws_size,
                              hipStream_t stream) {
    const int* x = (const int*)d_in[0];
    const int* src = (const int*)d_in[1];
    const int* dst = (const int*)d_in[2];
    const float* snorm_n = (const float*)d_in[3];
    const float* embed = (const float*)d_in[5];
    const float* Ws[3] = {(const float*)d_in[6], (const float*)d_in[11], (const float*)d_in[16]};
    const float* als[3] = {(const float*)d_in[7], (const float*)d_in[12], (const float*)d_in[17]};
    const float* ars[3] = {(const float*)d_in[8], (const float*)d_in[13], (const float*)d_in[18]};
    const float* gms[3] = {(const float*)d_in[9], (const float*)d_in[14], (const float*)d_in[19]};
    const float* bts[3] = {(const float*)d_in[10], (const float*)d_in[15], (const float*)d_in[20]};
    const float* cls1_w = (const float*)d_in[21];
    const float* cls1_b = (const float*)d_in[22];
    const float* cls2_w = (const float*)d_in[23];
    const float* cls2_b = (const float*)d_in[24];
    float* out = (float*)d_out;

    char* ws = (char*)d_ws;
    size_t off = 0;
    auto alloc = [&](size_t bytes) {
        void* p = ws + off;
        off = (off + bytes + 255) & ~(size_t)255;
        return p;
    };
    __half* h = (__half*)alloc((size_t)N_NODES * HDIM * 2);
    __half* feat_h = (__half*)alloc((size_t)N_NODES * HDIM * 2);
    float* el = (float*)alloc((size_t)N_NODES * 4 * 4);
    float* er = (float*)alloc((size_t)N_NODES * 4 * 4);
    int* rowstart = (int*)alloc((size_t)(N_NODES + 1) * 4);
    int* esrc = (int*)alloc((size_t)N_EDGES * 4);
    int* g_cursor = (int*)alloc((size_t)NB2 * 4);
    float* bn_part = (float*)alloc((size_t)3 * 16384 * 4);  // 3 layers x 64 buckets x 256
    int* bn_cnt = (int*)alloc(3 * 4);
    float* bn_scale = (float*)alloc(128 * 4);
    float* bn_shift = (float*)alloc(128 * 4);
    __half* wpkh = (__half*)alloc((size_t)3 * 16384 * 2);
    unsigned* g_bucket = (unsigned*)feat_h;  // 4 MB alias; CSR build finishes before gemm
    (void)ws_size; (void)in_sizes; (void)n_in; (void)out_size;

    k_wpack<<<(3 * 2048 + 255) / 256, 256, 0, stream>>>(Ws[0], Ws[1], Ws[2], wpkh,
                                                        bn_part, bn_cnt, g_cursor);
    k_partA<<<GA, 1024, 0, stream>>>(src, dst, g_cursor, g_bucket);
    k_partB<<<NB2, 1024, 0, stream>>>(g_bucket, g_cursor, rowstart, esrc);

    for (int L = 0; L < 3; L++) {
        const f16x8* wB = reinterpret_cast<const f16x8*>(wpkh + ((size_t)L << 14));
        k_gemm5<<<(N_NODES + 63) / 64, 256, 0, stream>>>(h, x, embed, wB,
                                                         feat_h, bn_scale, bn_shift,
                                                         als[L], ars[L], el, er, L == 0 ? 0 : 1);
        k_agg8<<<AGG_BLOCKS, 256, 0, stream>>>(feat_h, el, er, rowstart, esrc,
                                               snorm_n, h, bn_scale, bn_shift,
                                               gms[L], bts[L], bn_part + (size_t)L * 16384,
                                               bn_cnt + L, L);
    }

    k_classifier<<<(N_NODES + 15) / 16, 256, 0, stream>>>(h, cls1_w, cls1_b, cls2_w, cls2_b,
                                                          bn_scale, bn_shift, out);
}

// Round 3
// 341.205 us; speedup vs baseline: 5.5858x; 5.5858x over previous
//
#include <hip/hip_runtime.h>
#include <hip/hip_bf16.h>
#include <hip/hip_fp16.h>
#include <math.h>

constexpr int N_NODES = 50000;
constexpr int N_EDGES = 850000;
constexpr int HDIM = 128;   // H*D
constexpr int AGG_BLOCKS = N_NODES / 8;  // 6250
constexpr int BN_BUCKETS = 64;

typedef _Float16 f16x8 __attribute__((ext_vector_type(8)));
typedef float f32x4 __attribute__((ext_vector_type(4)));

// ---------------- CSR build: two-phase bucket sort ----------------
constexpr int NB2 = 128;                                // buckets
constexpr int RANGE2 = (N_NODES + NB2 - 1) / NB2;       // 391 nodes/bucket
constexpr int CAP = 8192;                               // bucket capacity (avg 6641)
constexpr int CHUNK = 8192;                             // edges per phase-A block
constexpr int GA = (N_EDGES + CHUNK - 1) / CHUNK;       // 104 blocks

__global__ void k_partA(const int* __restrict__ src, const int* __restrict__ dst,
                        int* __restrict__ g_cursor, unsigned* __restrict__ bucket) {
    __shared__ int hist[NB2];
    int tid = threadIdx.x;
    int e0 = blockIdx.x * CHUNK;
    int e1 = min(e0 + CHUNK, N_EDGES);
    if (tid < NB2) hist[tid] = 0;
    __syncthreads();
    for (int i = e0 + tid; i < e1; i += 1024) {
        int d = dst[i];
        atomicAdd(&hist[d / RANGE2], 1);
    }
    __syncthreads();
    int base = 0;
    if (tid < NB2) base = atomicAdd(&g_cursor[tid], hist[tid]);
    __syncthreads();
    if (tid < NB2) hist[tid] = base;
    __syncthreads();
    for (int i = e0 + tid; i < e1; i += 1024) {
        int d = dst[i];
        int s = src[i];
        int b = d / RANGE2;
        int p = atomicAdd(&hist[b], 1);
        bucket[b * CAP + p] = (unsigned)s | ((unsigned)(d - b * RANGE2) << 16);
    }
}

__global__ void k_partB(const unsigned* __restrict__ bucket, const int* __restrict__ cnts,
                        int* __restrict__ rowstart, int* __restrict__ esrc) {
    __shared__ int cnt_s[NB2];
    __shared__ int hist[RANGE2];
    __shared__ int lcur[RANGE2];
    __shared__ int wsum[7];
    int b = blockIdx.x, tid = threadIdx.x;
    int lo = b * RANGE2;
    int myCount = cnts[b];
    if (tid < NB2) cnt_s[tid] = cnts[tid];
    __syncthreads();
    for (int off = 1; off < NB2; off <<= 1) {
        int t = (tid < NB2 && tid >= off) ? cnt_s[tid - off] : 0;
        __syncthreads();
        if (tid < NB2) cnt_s[tid] += t;
        __syncthreads();
    }
    int base = cnt_s[b] - myCount;
    for (int j = tid; j < RANGE2; j += 1024) hist[j] = 0;
    __syncthreads();
    const unsigned* my = bucket + (size_t)b * CAP;
    for (int i = tid; i < myCount; i += 1024) atomicAdd(&hist[my[i] >> 16], 1);
    __syncthreads();
    int v = 0;
    if (tid < 448) v = (tid < RANGE2) ? hist[tid] : 0;
    int inc = v;
    int lane = tid & 63;
#pragma unroll
    for (int off = 1; off < 64; off <<= 1) {
        int t = __shfl_up(inc, off, 64);
        if (lane >= off) inc += t;
    }
    if (tid < 448 && lane == 63) wsum[tid >> 6] = inc;
    __syncthreads();
    if (tid < RANGE2) {
        int woff = 0;
        for (int w = 0; w < (tid >> 6); w++) woff += wsum[w];
        int excl = woff + inc - v;
        lcur[tid] = excl;
        int node = lo + tid;
        if (node < N_NODES) rowstart[node] = base + excl;
    }
    if (b == 0 && tid == 0) rowstart[N_NODES] = N_EDGES;
    __syncthreads();
    for (int i = tid; i < myCount; i += 1024) {
        unsigned p = my[i];
        int pos = atomicAdd(&lcur[p >> 16], 1);
        esrc[base + pos] = (int)(p & 0xFFFFu);
    }
}

// ---------------- W pre-pack into MFMA B-fragment layout + workspace zeroing ----------------
__global__ void k_wpack(const float* __restrict__ W0, const float* __restrict__ W1,
                        const float* __restrict__ W2, __half* __restrict__ wpk,
                        float* __restrict__ bn_part, int* __restrict__ g_cursor) {
    int gid = blockIdx.x * 256 + threadIdx.x;  // 24 * 256 = 6144
    {
        int z0 = gid * 8;
        if (z0 < 3 * BN_BUCKETS * 256) {
            float4 z = make_float4(0.f, 0.f, 0.f, 0.f);
            *reinterpret_cast<float4*>(&bn_part[z0]) = z;
            *reinterpret_cast<float4*>(&bn_part[z0 + 4]) = z;
        }
        if (gid < NB2) g_cursor[gid] = 0;
    }
    if (gid >= 3 * 2048) return;
    int L = gid >> 11;
    int rem = gid & 2047;
    int ct = rem >> 8;
    int kc = (rem >> 6) & 3;
    int l = rem & 63;
    const float* W = (L == 0) ? W0 : ((L == 1) ? W1 : W2);
    int c = ct * 16 + (l & 15);
    int k0 = kc * 32 + (l >> 4) * 8;
    __half tmp[8];
#pragma unroll
    for (int j = 0; j < 8; j++) tmp[j] = __float2half(W[(k0 + j) * HDIM + c]);
    *reinterpret_cast<float4*>(&wpk[((size_t)L << 14) + ((size_t)(ct * 4 + kc) * 64 + l) * 8]) =
        *reinterpret_cast<float4*>(tmp);
}

// ---------------- GEMM v5: MFMA 16x16x32_f16 ----------------
__global__ void k_gemm5(const __half* __restrict__ h, const int* __restrict__ xidx,
                        const float* __restrict__ embed, const f16x8* __restrict__ wB,
                        __half* __restrict__ feat_h, const float* __restrict__ bnsc,
                        const float* __restrict__ bnsh, const float* __restrict__ al,
                        const float* __restrict__ ar, float* __restrict__ el,
                        float* __restrict__ er, int mode) {
    __shared__ __half sf[4][16][136];  // per-wave 16x128 fp16 tile (+8 pad), 17.4 KB
    int tid = threadIdx.x;
    int w = tid >> 6, lane = tid & 63;
    int r = lane & 15, kg = lane >> 4;
    int wbase = blockIdx.x * 64 + w * 16;
    int n = wbase + r;
    bool ok = n < N_NODES;

    // ---- A fragments: aF[kc][j] = act[n][kc*32 + kg*8 + j] ----
    f16x8 aF[4];
#pragma unroll
    for (int kc = 0; kc < 4; kc++)
#pragma unroll
        for (int j = 0; j < 8; j++) aF[kc][j] = (_Float16)0.f;
    if (ok) {
        if (mode == 0) {
            int xi = xidx[n];
            const float* ep = embed + (size_t)xi * HDIM;
#pragma unroll
            for (int kc = 0; kc < 4; kc++) {
                int c0 = kc * 32 + kg * 8;
                float4 e0 = *reinterpret_cast<const float4*>(ep + c0);
                float4 e1 = *reinterpret_cast<const float4*>(ep + c0 + 4);
                aF[kc][0] = (_Float16)e0.x; aF[kc][1] = (_Float16)e0.y;
                aF[kc][2] = (_Float16)e0.z; aF[kc][3] = (_Float16)e0.w;
                aF[kc][4] = (_Float16)e1.x; aF[kc][5] = (_Float16)e1.y;
                aF[kc][6] = (_Float16)e1.z; aF[kc][7] = (_Float16)e1.w;
            }
        } else {
            const __half* hp = h + (size_t)n * HDIM;
#pragma unroll
            for (int kc = 0; kc < 4; kc++) {
                int c0 = kc * 32 + kg * 8;
                float4 raw = *reinterpret_cast<const float4*>(hp + c0);
                const __half2* u = reinterpret_cast<const __half2*>(&raw);
                float4 sc0 = *reinterpret_cast<const float4*>(&bnsc[c0]);
                float4 sc1 = *reinterpret_cast<const float4*>(&bnsc[c0 + 4]);
                float4 sh0 = *reinterpret_cast<const float4*>(&bnsh[c0]);
                float4 sh1 = *reinterpret_cast<const float4*>(&bnsh[c0 + 4]);
                float scv[8] = {sc0.x, sc0.y, sc0.z, sc0.w, sc1.x, sc1.y, sc1.z, sc1.w};
                float shv[8] = {sh0.x, sh0.y, sh0.z, sh0.w, sh1.x, sh1.y, sh1.z, sh1.w};
                float vv[8];
#pragma unroll
                for (int t = 0; t < 4; t++) {
                    vv[2 * t] = __half2float(__low2half(u[t]));
                    vv[2 * t + 1] = __half2float(__high2half(u[t]));
                }
#pragma unroll
                for (int j = 0; j < 8; j++) {
                    float t = vv[j] * scv[j] + shv[j];
                    t = (t > 0.f) ? t : expm1f(t);
                    aF[kc][j] = (_Float16)t;
                }
            }
        }
    }

    // ---- MFMA main: acc[ct] over 4 K-chunks ----
    f32x4 acc[8] = {};
#pragma unroll
    for (int kc = 0; kc < 4; kc++) {
#pragma unroll
        for (int ct = 0; ct < 8; ct++) {
            f16x8 bF = wB[(ct * 4 + kc) * 64 + lane];
            acc[ct] = __builtin_amdgcn_mfma_f32_16x16x32_f16(aF[kc], bF, acc[ct], 0, 0, 0);
        }
    }

    // ---- feat store: C/D layout col=lane&15 (within ct), row=kg*4+reg ----
#pragma unroll
    for (int ct = 0; ct < 8; ct++)
#pragma unroll
        for (int reg = 0; reg < 4; reg++)
            sf[w][kg * 4 + reg][ct * 16 + r] = __float2half(acc[ct][reg]);
    __syncthreads();
#pragma unroll
    for (int q = 0; q < 4; q++) {
        int row = q * 4 + kg;
        int n2 = wbase + row;
        if (n2 < N_NODES) {
            float4 v = *reinterpret_cast<const float4*>(&sf[w][row][r * 8]);
            *reinterpret_cast<float4*>(&feat_h[(size_t)n2 * HDIM + r * 8]) = v;
        }
    }

    // ---- fused el/er: head hd covers ct=2hd, 2hd+1; reduce over 16 lanes (cols) ----
    float alq[8], arq[8];
#pragma unroll
    for (int ct = 0; ct < 8; ct++) {
        alq[ct] = al[ct * 16 + r];
        arq[ct] = ar[ct * 16 + r];
    }
#pragma unroll
    for (int hd = 0; hd < 4; hd++) {
        float pl[4], pr[4];
#pragma unroll
        for (int reg = 0; reg < 4; reg++) {
            pl[reg] = acc[2 * hd][reg] * alq[2 * hd] + acc[2 * hd + 1][reg] * alq[2 * hd + 1];
            pr[reg] = acc[2 * hd][reg] * arq[2 * hd] + acc[2 * hd + 1][reg] * arq[2 * hd + 1];
        }
#pragma unroll
        for (int off = 1; off < 16; off <<= 1)
#pragma unroll
            for (int reg = 0; reg < 4; reg++) {
                pl[reg] += __shfl_xor(pl[reg], off, 64);
                pr[reg] += __shfl_xor(pr[reg], off, 64);
            }
        if (r == 0) {
#pragma unroll
            for (int reg = 0; reg < 4; reg++) {
                int n2 = wbase + kg * 4 + reg;
                if (n2 < N_NODES) {
                    el[n2 * 4 + hd] = pl[reg];
                    er[n2 * 4 + hd] = pr[reg];
                }
            }
        }
    }
}

// ---------------- aggregation v9: v7 hot loop + BN partials (no fences) ----------------
__global__ void k_agg9(const __half* __restrict__ feat_h, const float* __restrict__ el,
                       const float* __restrict__ er, const int* __restrict__ rowstart,
                       const int* __restrict__ esrc, const float* __restrict__ snorm_n,
                       __half* __restrict__ h, const float* __restrict__ bnsc,
                       const float* __restrict__ bnsh, float* __restrict__ bn_part,
                       int layer) {
    __shared__ __align__(16) int2 lds[4][2][2][32][4];  // [wave][h2][buf][slot][head], 16 KB
    int tid = threadIdx.x;
    int wave = tid >> 6, lane = tid & 63;
    int h2 = lane >> 5, hl = lane & 31;
    int dp = hl & 15, epair = hl >> 4, head = dp >> 2;
    int n = blockIdx.x * 8 + wave * 2 + h2;   // 6250 blocks * 8 = 50000 exactly
    int e0 = rowstart[n];
    int deg = rowstart[n + 1] - e0;           // >= 1 (self loops)
    int dmax = max(deg, __shfl_xor(deg, 32, 64));
    float4 er4 = *(const float4*)&er[n * 4];
    const float4* fp = reinterpret_cast<const float4*>(feat_h);
    float s = 0.f;
    float a[8] = {};
    int nch = (dmax + 31) >> 5;

    int idx0 = e0 + min(hl, deg - 1);
    int sidx_p = esrc[idx0];
    float4 el_p = *(const float4*)&el[sidx_p * 4];
    bool val_p = hl < deg;

    for (int c = 0; c < nch; c++) {
        float w0 = 0.f, w1 = 0.f, w2 = 0.f, w3 = 0.f;
        int sv = sidx_p;
        if (val_p) {
            float ex = el_p.x + er4.x, ey = el_p.y + er4.y;
            float ez = el_p.z + er4.z, ew = el_p.w + er4.w;
            ex = fmaxf(ex, 0.f) + 0.2f * fminf(ex, 0.f);
            ey = fmaxf(ey, 0.f) + 0.2f * fminf(ey, 0.f);
            ez = fmaxf(ez, 0.f) + 0.2f * fminf(ez, 0.f);
            ew = fmaxf(ew, 0.f) + 0.2f * fminf(ew, 0.f);
            w0 = __expf(ex); w1 = __expf(ey); w2 = __expf(ez); w3 = __expf(ew);
        }
        int4* wp = reinterpret_cast<int4*>(&lds[wave][h2][c & 1][hl][0]);
        wp[0] = make_int4(sv, __float_as_int(w0), sv, __float_as_int(w1));
        wp[1] = make_int4(sv, __float_as_int(w2), sv, __float_as_int(w3));
        if (c + 1 < nch) {
            int slot = (c + 1) * 32 + hl;
            int idx = e0 + min(slot, deg - 1);
            sidx_p = esrc[idx];
            el_p = *(const float4*)&el[sidx_p * 4];
            val_p = slot < deg;
        }
        int cnt = min(32, dmax - c * 32);
        int iters = (cnt + 1) >> 1;
#pragma unroll 2
        for (int j = 0; j < iters; j++) {
            int2 rec = lds[wave][h2][c & 1][j * 2 + epair][head];
            float w = __int_as_float(rec.y);
            float4 fv = fp[(size_t)rec.x * 16 + dp];
            __half2 p0 = *(__half2*)&fv.x, p1 = *(__half2*)&fv.y;
            __half2 p2 = *(__half2*)&fv.z, p3 = *(__half2*)&fv.w;
            a[0] = fmaf(__half2float(__low2half(p0)), w, a[0]);
            a[1] = fmaf(__half2float(__high2half(p0)), w, a[1]);
            a[2] = fmaf(__half2float(__low2half(p1)), w, a[2]);
            a[3] = fmaf(__half2float(__high2half(p1)), w, a[3]);
            a[4] = fmaf(__half2float(__low2half(p2)), w, a[4]);
            a[5] = fmaf(__half2float(__high2half(p2)), w, a[5]);
            a[6] = fmaf(__half2float(__low2half(p3)), w, a[6]);
            a[7] = fmaf(__half2float(__high2half(p3)), w, a[7]);
            s += w;
        }
    }
#pragma unroll
    for (int k = 0; k < 8; k++) a[k] += __shfl_xor(a[k], 16, 64);
    s += __shfl_xor(s, 16, 64);
    float r[8] = {};
    if (epair == 0) {
        float inv = 1.f / s;
        int d0 = dp * 8;
#pragma unroll
        for (int k = 0; k < 8; k++) r[k] = a[k] * inv;
        if (layer > 0) {
            float4 hraw = *reinterpret_cast<const float4*>(&h[(size_t)n * HDIM + d0]);
            __half2 q0 = *(__half2*)&hraw.x, q1 = *(__half2*)&hraw.y;
            __half2 q2 = *(__half2*)&hraw.z, q3 = *(__half2*)&hraw.w;
            float hv[8] = {__half2float(__low2half(q0)), __half2float(__high2half(q0)),
                           __half2float(__low2half(q1)), __half2float(__high2half(q1)),
                           __half2float(__low2half(q2)), __half2float(__high2half(q2)),
                           __half2float(__low2half(q3)), __half2float(__high2half(q3))};
            float4 sc0 = *reinterpret_cast<const float4*>(&bnsc[d0]);
            float4 sc1 = *reinterpret_cast<const float4*>(&bnsc[d0 + 4]);
            float4 sh0 = *reinterpret_cast<const float4*>(&bnsh[d0]);
            float4 sh1 = *reinterpret_cast<const float4*>(&bnsh[d0 + 4]);
            float scv[8] = {sc0.x, sc0.y, sc0.z, sc0.w, sc1.x, sc1.y, sc1.z, sc1.w};
            float shv[8] = {sh0.x, sh0.y, sh0.z, sh0.w, sh1.x, sh1.y, sh1.z, sh1.w};
#pragma unroll
            for (int k = 0; k < 8; k++) {
                float t = hv[k] * scv[k] + shv[k];
                t = (t > 0.f) ? t : expm1f(t);
                r[k] += t;
                r[k] = (r[k] > 0.f) ? r[k] : expm1f(r[k]);
            }
        }
        float sn = snorm_n[n];
#pragma unroll
        for (int k = 0; k < 8; k++) r[k] *= sn;
        float4 outv;
        *(__half2*)&outv.x = __floats2half2_rn(r[0], r[1]);
        *(__half2*)&outv.y = __floats2half2_rn(r[2], r[3]);
        *(__half2*)&outv.z = __floats2half2_rn(r[4], r[5]);
        *(__half2*)&outv.w = __floats2half2_rn(r[6], r[7]);
        *reinterpret_cast<float4*>(&h[(size_t)n * HDIM + d0]) = outv;
    }

    // ---- BN partials: per-block LDS reduce + one atomicAdd per (c,which); NO fences ----
    float* bsum = reinterpret_cast<float*>(lds);   // 2048 floats used (of 4096)
    __syncthreads();          // all waves done with their lds hot-loop regions
    if (epair == 0) {
        int n8 = wave * 2 + h2;
        int cbase = n8 * 128 + dp * 8;
#pragma unroll
        for (int k = 0; k < 8; k++) {
            bsum[cbase + k] = r[k];
            bsum[1024 + cbase + k] = r[k] * r[k];
        }
    }
    __syncthreads();
    {
        int c = tid & 127, which = tid >> 7;   // which: 0=sum, 1=sumsq
        float v = 0.f;
#pragma unroll
        for (int n8 = 0; n8 < 8; n8++) v += bsum[which * 1024 + n8 * 128 + c];
        atomicAdd(&bn_part[(blockIdx.x & (BN_BUCKETS - 1)) * 256 + which * 128 + c], v);
    }
}

// ---------------- BN finalize: 1 block, reduce buckets -> scale/shift ----------------
__global__ void k_bnfin(const float* __restrict__ bn_part, const float* __restrict__ gamma,
                        const float* __restrict__ beta, float* __restrict__ scale,
                        float* __restrict__ shift) {
    __shared__ float red[256];
    int tid = threadIdx.x;
    int c = tid & 127, which = tid >> 7;
    float t = 0.f;
    for (int b = 0; b < BN_BUCKETS; b++) t += bn_part[b * 256 + which * 128 + c];
    red[tid] = t;
    __syncthreads();
    if (tid < 128) {
        float mu = red[tid] * (1.f / N_NODES);
        float var = red[128 + tid] * (1.f / N_NODES) - mu * mu;
        float sc = gamma[tid] * rsqrtf(var + 1e-5f);
        scale[tid] = sc;
        shift[tid] = beta[tid] - mu * sc;
    }
}

// ---------------- classifier (h fp16) ----------------
__global__ void k_classifier(const __half* __restrict__ h, const float* __restrict__ W1,
                             const float* __restrict__ b1, const float* __restrict__ W2,
                             const float* __restrict__ b2, const float* __restrict__ bnsc,
                             const float* __restrict__ bnsh, float* __restrict__ out) {
    __shared__ float hs[16][128];
    int tid = threadIdx.x;
    int nbase = blockIdx.x * 16;
    for (int i = tid; i < 16 * 128; i += 256) {
        int r = i >> 7, c = i & 127;
        int n = nbase + r;
        float v = 0.f;
        if (n < N_NODES) {
            v = __half2float(h[(size_t)n * HDIM + c]) * bnsc[c] + bnsh[c];
            v = (v > 0.f) ? v : expm1f(v);
        }
        hs[r][c] = v;
    }
    __syncthreads();
    int j = tid & 63;
    int g = tid >> 6;
    float bj = b1[j];
    float acc[4] = {bj, bj, bj, bj};
    for (int k = 0; k < 128; k++) {
        float w = W1[k * 64 + j];
#pragma unroll
        for (int i = 0; i < 4; i++) acc[i] += hs[g * 4 + i][k] * w;
    }
    float w20 = W2[j * 2], w21 = W2[j * 2 + 1];
    float res[8];
#pragma unroll
    for (int i = 0; i < 4; i++) {
        float hid = fmaxf(acc[i], 0.f);
        res[2 * i] = hid * w20;
        res[2 * i + 1] = hid * w21;
    }
#pragma unroll
    for (int off = 1; off < 64; off <<= 1)
#pragma unroll
        for (int i = 0; i < 8; i++) res[i] += __shfl_xor(res[i], off, 64);
    if (j < 8) {
        int n = nbase + g * 4 + (j >> 1);
        if (n < N_NODES) out[n * 2 + (j & 1)] = res[j] + b2[j & 1];
    }
}

// ----------------------------------------------------------------
extern "C" void kernel_launch(void* const* d_in, const int* in_sizes, int n_in,
                              void* d_out, int out_size, void* d_ws, size_t ws_size,
                              hipStream_t stream) {
    const int* x = (const int*)d_in[0];
    const int* src = (const int*)d_in[1];
    const int* dst = (const int*)d_in[2];
    const float* snorm_n = (const float*)d_in[3];
    const float* embed = (const float*)d_in[5];
    const float* Ws[3] = {(const float*)d_in[6], (const float*)d_in[11], (const float*)d_in[16]};
    const float* als[3] = {(const float*)d_in[7], (const float*)d_in[12], (const float*)d_in[17]};
    const float* ars[3] = {(const float*)d_in[8], (const float*)d_in[13], (const float*)d_in[18]};
    const float* gms[3] = {(const float*)d_in[9], (const float*)d_in[14], (const float*)d_in[19]};
    const float* bts[3] = {(const float*)d_in[10], (const float*)d_in[15], (const float*)d_in[20]};
    const float* cls1_w = (const float*)d_in[21];
    const float* cls1_b = (const float*)d_in[22];
    const float* cls2_w = (const float*)d_in[23];
    const float* cls2_b = (const float*)d_in[24];
    float* out = (float*)d_out;

    char* ws = (char*)d_ws;
    size_t off = 0;
    auto alloc = [&](size_t bytes) {
        void* p = ws + off;
        off = (off + bytes + 255) & ~(size_t)255;
        return p;
    };
    __half* h = (__half*)alloc((size_t)N_NODES * HDIM * 2);
    __half* feat_h = (__half*)alloc((size_t)N_NODES * HDIM * 2);
    float* el = (float*)alloc((size_t)N_NODES * 4 * 4);
    float* er = (float*)alloc((size_t)N_NODES * 4 * 4);
    int* rowstart = (int*)alloc((size_t)(N_NODES + 1) * 4);
    int* esrc = (int*)alloc((size_t)N_EDGES * 4);
    int* g_cursor = (int*)alloc((size_t)NB2 * 4);
    float* bn_part = (float*)alloc((size_t)3 * BN_BUCKETS * 256 * 4);
    float* bn_scale = (float*)alloc(128 * 4);
    float* bn_shift = (float*)alloc(128 * 4);
    __half* wpkh = (__half*)alloc((size_t)3 * 16384 * 2);
    unsigned* g_bucket = (unsigned*)feat_h;  // 4 MB alias; CSR build finishes before gemm
    (void)ws_size; (void)in_sizes; (void)n_in; (void)out_size;

    k_wpack<<<(3 * 2048 + 255) / 256, 256, 0, stream>>>(Ws[0], Ws[1], Ws[2], wpkh,
                                                        bn_part, g_cursor);
    k_partA<<<GA, 1024, 0, stream>>>(src, dst, g_cursor, g_bucket);
    k_partB<<<NB2, 1024, 0, stream>>>(g_bucket, g_cursor, rowstart, esrc);

    for (int L = 0; L < 3; L++) {
        const f16x8* wB = reinterpret_cast<const f16x8*>(wpkh + ((size_t)L << 14));
        k_gemm5<<<(N_NODES + 63) / 64, 256, 0, stream>>>(h, x, embed, wB,
                                                         feat_h, bn_scale, bn_shift,
                                                         als[L], ars[L], el, er, L == 0 ? 0 : 1);
        k_agg9<<<AGG_BLOCKS, 256, 0, stream>>>(feat_h, el, er, rowstart, esrc,
                                               snorm_n, h, bn_scale, bn_shift,
                                               bn_part + (size_t)L * BN_BUCKETS * 256, L);
        k_bnfin<<<1, 256, 0, stream>>>(bn_part + (size_t)L * BN_BUCKETS * 256,
                                       gms[L], bts[L], bn_scale, bn_shift);
    }

    k_classifier<<<(N_NODES + 15) / 16, 256, 0, stream>>>(h, cls1_w, cls1_b, cls2_w, cls2_b,
                                                          bn_scale, bn_shift, out);
}

// Round 4
// 339.537 us; speedup vs baseline: 5.6133x; 1.0049x over previous
//
#include <hip/hip_runtime.h>
#include <hip/hip_bf16.h>
#include <hip/hip_fp16.h>
#include <math.h>

constexpr int N_NODES = 50000;
constexpr int N_EDGES = 850000;
constexpr int HDIM = 128;   // H*D
constexpr int AGG_BLOCKS = N_NODES / 8;  // 6250
constexpr int BN_BUCKETS = 16;

typedef _Float16 f16x8 __attribute__((ext_vector_type(8)));
typedef float f32x4 __attribute__((ext_vector_type(4)));

// ---------------- CSR build: two-phase bucket sort ----------------
constexpr int NB2 = 128;                                // buckets
constexpr int RANGE2 = (N_NODES + NB2 - 1) / NB2;       // 391 nodes/bucket
constexpr int CAP = 8192;                               // bucket capacity (avg 6641)
constexpr int CHUNK = 8192;                             // edges per phase-A block
constexpr int GA = (N_EDGES + CHUNK - 1) / CHUNK;       // 104 blocks

__global__ void k_partA(const int* __restrict__ src, const int* __restrict__ dst,
                        int* __restrict__ g_cursor, unsigned* __restrict__ bucket) {
    __shared__ int hist[NB2];
    int tid = threadIdx.x;
    int e0 = blockIdx.x * CHUNK;
    int e1 = min(e0 + CHUNK, N_EDGES);
    if (tid < NB2) hist[tid] = 0;
    __syncthreads();
    for (int i = e0 + tid; i < e1; i += 1024) {
        int d = dst[i];
        atomicAdd(&hist[d / RANGE2], 1);
    }
    __syncthreads();
    int base = 0;
    if (tid < NB2) base = atomicAdd(&g_cursor[tid], hist[tid]);
    __syncthreads();
    if (tid < NB2) hist[tid] = base;
    __syncthreads();
    for (int i = e0 + tid; i < e1; i += 1024) {
        int d = dst[i];
        int s = src[i];
        int b = d / RANGE2;
        int p = atomicAdd(&hist[b], 1);
        bucket[b * CAP + p] = (unsigned)s | ((unsigned)(d - b * RANGE2) << 16);
    }
}

__global__ void k_partB(const unsigned* __restrict__ bucket, const int* __restrict__ cnts,
                        int* __restrict__ rowstart, int* __restrict__ esrc) {
    __shared__ int cnt_s[NB2];
    __shared__ int hist[RANGE2];
    __shared__ int lcur[RANGE2];
    __shared__ int wsum[7];
    int b = blockIdx.x, tid = threadIdx.x;
    int lo = b * RANGE2;
    int myCount = cnts[b];
    if (tid < NB2) cnt_s[tid] = cnts[tid];
    __syncthreads();
    for (int off = 1; off < NB2; off <<= 1) {
        int t = (tid < NB2 && tid >= off) ? cnt_s[tid - off] : 0;
        __syncthreads();
        if (tid < NB2) cnt_s[tid] += t;
        __syncthreads();
    }
    int base = cnt_s[b] - myCount;
    for (int j = tid; j < RANGE2; j += 1024) hist[j] = 0;
    __syncthreads();
    const unsigned* my = bucket + (size_t)b * CAP;
    for (int i = tid; i < myCount; i += 1024) atomicAdd(&hist[my[i] >> 16], 1);
    __syncthreads();
    int v = 0;
    if (tid < 448) v = (tid < RANGE2) ? hist[tid] : 0;
    int inc = v;
    int lane = tid & 63;
#pragma unroll
    for (int off = 1; off < 64; off <<= 1) {
        int t = __shfl_up(inc, off, 64);
        if (lane >= off) inc += t;
    }
    if (tid < 448 && lane == 63) wsum[tid >> 6] = inc;
    __syncthreads();
    if (tid < RANGE2) {
        int woff = 0;
        for (int w = 0; w < (tid >> 6); w++) woff += wsum[w];
        int excl = woff + inc - v;
        lcur[tid] = excl;
        int node = lo + tid;
        if (node < N_NODES) rowstart[node] = base + excl;
    }
    if (b == 0 && tid == 0) rowstart[N_NODES] = N_EDGES;
    __syncthreads();
    for (int i = tid; i < myCount; i += 1024) {
        unsigned p = my[i];
        int pos = atomicAdd(&lcur[p >> 16], 1);
        esrc[base + pos] = (int)(p & 0xFFFFu);
    }
}

// ---------------- W pre-pack into MFMA B-fragment layout + workspace zeroing ----------------
__global__ void k_wpack(const float* __restrict__ W0, const float* __restrict__ W1,
                        const float* __restrict__ W2, __half* __restrict__ wpk,
                        float* __restrict__ bn_part, int* __restrict__ g_cursor) {
    int gid = blockIdx.x * 256 + threadIdx.x;  // 24 * 256 = 6144
    {
        int z0 = gid * 8;
        if (z0 < 3 * BN_BUCKETS * 256) {
            float4 z = make_float4(0.f, 0.f, 0.f, 0.f);
            *reinterpret_cast<float4*>(&bn_part[z0]) = z;
            *reinterpret_cast<float4*>(&bn_part[z0 + 4]) = z;
        }
        if (gid < NB2) g_cursor[gid] = 0;
    }
    if (gid >= 3 * 2048) return;
    int L = gid >> 11;
    int rem = gid & 2047;
    int ct = rem >> 8;
    int kc = (rem >> 6) & 3;
    int l = rem & 63;
    const float* W = (L == 0) ? W0 : ((L == 1) ? W1 : W2);
    int c = ct * 16 + (l & 15);
    int k0 = kc * 32 + (l >> 4) * 8;
    __half tmp[8];
#pragma unroll
    for (int j = 0; j < 8; j++) tmp[j] = __float2half(W[(k0 + j) * HDIM + c]);
    *reinterpret_cast<float4*>(&wpk[((size_t)L << 14) + ((size_t)(ct * 4 + kc) * 64 + l) * 8]) =
        *reinterpret_cast<float4*>(tmp);
}

// ---------------- GEMM v6: MFMA 16x16x32_f16, BN finalize fused in prologue ----------------
__global__ void k_gemm6(const __half* __restrict__ h, const int* __restrict__ xidx,
                        const float* __restrict__ embed, const f16x8* __restrict__ wB,
                        __half* __restrict__ feat_h, const float* __restrict__ bn_prev,
                        const float* __restrict__ gamma, const float* __restrict__ beta,
                        const float* __restrict__ al, const float* __restrict__ ar,
                        float* __restrict__ el, float* __restrict__ er, int mode) {
    __shared__ __half sf[4][16][136];  // per-wave 16x128 fp16 tile (+8 pad), 17.4 KB
    __shared__ __align__(16) float s_sc[128];
    __shared__ __align__(16) float s_sh[128];
    int tid = threadIdx.x;
    // ---- BN finalize prologue (redundant per block; bn_prev is L2-resident 16 KB) ----
    if (mode != 0) {
        float* red = reinterpret_cast<float*>(sf);   // alias; sf written after
        int c = tid & 127, which = tid >> 7;
        float t = 0.f;
#pragma unroll
        for (int b = 0; b < BN_BUCKETS; b++) t += bn_prev[b * 256 + which * 128 + c];
        red[tid] = t;
        __syncthreads();
        if (tid < 128) {
            float mu = red[tid] * (1.f / N_NODES);
            float var = red[128 + tid] * (1.f / N_NODES) - mu * mu;
            float sc = gamma[tid] * rsqrtf(var + 1e-5f);
            s_sc[tid] = sc;
            s_sh[tid] = beta[tid] - mu * sc;
        }
        __syncthreads();
    }
    int w = tid >> 6, lane = tid & 63;
    int r = lane & 15, kg = lane >> 4;
    int wbase = blockIdx.x * 64 + w * 16;
    int n = wbase + r;
    bool ok = n < N_NODES;

    // ---- A fragments: aF[kc][j] = act[n][kc*32 + kg*8 + j] ----
    f16x8 aF[4];
#pragma unroll
    for (int kc = 0; kc < 4; kc++)
#pragma unroll
        for (int j = 0; j < 8; j++) aF[kc][j] = (_Float16)0.f;
    if (ok) {
        if (mode == 0) {
            int xi = xidx[n];
            const float* ep = embed + (size_t)xi * HDIM;
#pragma unroll
            for (int kc = 0; kc < 4; kc++) {
                int c0 = kc * 32 + kg * 8;
                float4 e0 = *reinterpret_cast<const float4*>(ep + c0);
                float4 e1 = *reinterpret_cast<const float4*>(ep + c0 + 4);
                aF[kc][0] = (_Float16)e0.x; aF[kc][1] = (_Float16)e0.y;
                aF[kc][2] = (_Float16)e0.z; aF[kc][3] = (_Float16)e0.w;
                aF[kc][4] = (_Float16)e1.x; aF[kc][5] = (_Float16)e1.y;
                aF[kc][6] = (_Float16)e1.z; aF[kc][7] = (_Float16)e1.w;
            }
        } else {
            const __half* hp = h + (size_t)n * HDIM;
#pragma unroll
            for (int kc = 0; kc < 4; kc++) {
                int c0 = kc * 32 + kg * 8;
                float4 raw = *reinterpret_cast<const float4*>(hp + c0);
                const __half2* u = reinterpret_cast<const __half2*>(&raw);
                float4 sc0 = *reinterpret_cast<const float4*>(&s_sc[c0]);
                float4 sc1 = *reinterpret_cast<const float4*>(&s_sc[c0 + 4]);
                float4 sh0 = *reinterpret_cast<const float4*>(&s_sh[c0]);
                float4 sh1 = *reinterpret_cast<const float4*>(&s_sh[c0 + 4]);
                float scv[8] = {sc0.x, sc0.y, sc0.z, sc0.w, sc1.x, sc1.y, sc1.z, sc1.w};
                float shv[8] = {sh0.x, sh0.y, sh0.z, sh0.w, sh1.x, sh1.y, sh1.z, sh1.w};
                float vv[8];
#pragma unroll
                for (int t = 0; t < 4; t++) {
                    vv[2 * t] = __half2float(__low2half(u[t]));
                    vv[2 * t + 1] = __half2float(__high2half(u[t]));
                }
#pragma unroll
                for (int j = 0; j < 8; j++) {
                    float t = vv[j] * scv[j] + shv[j];
                    t = (t > 0.f) ? t : expm1f(t);
                    aF[kc][j] = (_Float16)t;
                }
            }
        }
    }
    if (mode != 0) __syncthreads();  // red alias done before sf writes

    // ---- MFMA main: acc[ct] over 4 K-chunks ----
    f32x4 acc[8] = {};
#pragma unroll
    for (int kc = 0; kc < 4; kc++) {
#pragma unroll
        for (int ct = 0; ct < 8; ct++) {
            f16x8 bF = wB[(ct * 4 + kc) * 64 + lane];
            acc[ct] = __builtin_amdgcn_mfma_f32_16x16x32_f16(aF[kc], bF, acc[ct], 0, 0, 0);
        }
    }

    // ---- feat store: C/D layout col=lane&15 (within ct), row=kg*4+reg ----
#pragma unroll
    for (int ct = 0; ct < 8; ct++)
#pragma unroll
        for (int reg = 0; reg < 4; reg++)
            sf[w][kg * 4 + reg][ct * 16 + r] = __float2half(acc[ct][reg]);
    __syncthreads();
#pragma unroll
    for (int q = 0; q < 4; q++) {
        int row = q * 4 + kg;
        int n2 = wbase + row;
        if (n2 < N_NODES) {
            float4 v = *reinterpret_cast<const float4*>(&sf[w][row][r * 8]);
            *reinterpret_cast<float4*>(&feat_h[(size_t)n2 * HDIM + r * 8]) = v;
        }
    }

    // ---- fused el/er: head hd covers ct=2hd, 2hd+1; reduce over 16 lanes (cols) ----
    float alq[8], arq[8];
#pragma unroll
    for (int ct = 0; ct < 8; ct++) {
        alq[ct] = al[ct * 16 + r];
        arq[ct] = ar[ct * 16 + r];
    }
#pragma unroll
    for (int hd = 0; hd < 4; hd++) {
        float pl[4], pr[4];
#pragma unroll
        for (int reg = 0; reg < 4; reg++) {
            pl[reg] = acc[2 * hd][reg] * alq[2 * hd] + acc[2 * hd + 1][reg] * alq[2 * hd + 1];
            pr[reg] = acc[2 * hd][reg] * arq[2 * hd] + acc[2 * hd + 1][reg] * arq[2 * hd + 1];
        }
#pragma unroll
        for (int off = 1; off < 16; off <<= 1)
#pragma unroll
            for (int reg = 0; reg < 4; reg++) {
                pl[reg] += __shfl_xor(pl[reg], off, 64);
                pr[reg] += __shfl_xor(pr[reg], off, 64);
            }
        if (r == 0) {
#pragma unroll
            for (int reg = 0; reg < 4; reg++) {
                int n2 = wbase + kg * 4 + reg;
                if (n2 < N_NODES) {
                    el[n2 * 4 + hd] = pl[reg];
                    er[n2 * 4 + hd] = pr[reg];
                }
            }
        }
    }
}

// ---------------- aggregation v10: BN finalize prologue + hot loop + BN partials ----------------
__global__ void k_agg10(const __half* __restrict__ feat_h, const float* __restrict__ el,
                        const float* __restrict__ er, const int* __restrict__ rowstart,
                        const int* __restrict__ esrc, const float* __restrict__ snorm_n,
                        __half* __restrict__ h, const float* __restrict__ bn_prev,
                        const float* __restrict__ gamma, const float* __restrict__ beta,
                        float* __restrict__ bn_cur, int layer) {
    __shared__ __align__(16) int2 lds[4][2][2][32][4];  // [wave][h2][buf][slot][head], 16 KB
    __shared__ __align__(16) float s_sc[128];
    __shared__ __align__(16) float s_sh[128];
    int tid = threadIdx.x;
    // ---- BN finalize prologue for residual path (layer > 0) ----
    if (layer > 0) {
        float* red = reinterpret_cast<float*>(lds);  // alias; lds rewritten after barrier
        int c = tid & 127, which = tid >> 7;
        float t = 0.f;
#pragma unroll
        for (int b = 0; b < BN_BUCKETS; b++) t += bn_prev[b * 256 + which * 128 + c];
        red[tid] = t;
        __syncthreads();
        if (tid < 128) {
            float mu = red[tid] * (1.f / N_NODES);
            float var = red[128 + tid] * (1.f / N_NODES) - mu * mu;
            float sc = gamma[tid] * rsqrtf(var + 1e-5f);
            s_sc[tid] = sc;
            s_sh[tid] = beta[tid] - mu * sc;
        }
        __syncthreads();
    }
    int wave = tid >> 6, lane = tid & 63;
    int h2 = lane >> 5, hl = lane & 31;
    int dp = hl & 15, epair = hl >> 4, head = dp >> 2;
    int n = blockIdx.x * 8 + wave * 2 + h2;   // 6250 blocks * 8 = 50000 exactly
    int e0 = rowstart[n];
    int deg = rowstart[n + 1] - e0;           // >= 1 (self loops)
    int dmax = max(deg, __shfl_xor(deg, 32, 64));
    float4 er4 = *(const float4*)&er[n * 4];
    const float4* fp = reinterpret_cast<const float4*>(feat_h);
    float s = 0.f;
    float a[8] = {};
    int nch = (dmax + 31) >> 5;

    int idx0 = e0 + min(hl, deg - 1);
    int sidx_p = esrc[idx0];
    float4 el_p = *(const float4*)&el[sidx_p * 4];
    bool val_p = hl < deg;

    for (int c = 0; c < nch; c++) {
        float w0 = 0.f, w1 = 0.f, w2 = 0.f, w3 = 0.f;
        int sv = sidx_p;
        if (val_p) {
            float ex = el_p.x + er4.x, ey = el_p.y + er4.y;
            float ez = el_p.z + er4.z, ew = el_p.w + er4.w;
            ex = fmaxf(ex, 0.f) + 0.2f * fminf(ex, 0.f);
            ey = fmaxf(ey, 0.f) + 0.2f * fminf(ey, 0.f);
            ez = fmaxf(ez, 0.f) + 0.2f * fminf(ez, 0.f);
            ew = fmaxf(ew, 0.f) + 0.2f * fminf(ew, 0.f);
            w0 = __expf(ex); w1 = __expf(ey); w2 = __expf(ez); w3 = __expf(ew);
        }
        int4* wp = reinterpret_cast<int4*>(&lds[wave][h2][c & 1][hl][0]);
        wp[0] = make_int4(sv, __float_as_int(w0), sv, __float_as_int(w1));
        wp[1] = make_int4(sv, __float_as_int(w2), sv, __float_as_int(w3));
        if (c + 1 < nch) {
            int slot = (c + 1) * 32 + hl;
            int idx = e0 + min(slot, deg - 1);
            sidx_p = esrc[idx];
            el_p = *(const float4*)&el[sidx_p * 4];
            val_p = slot < deg;
        }
        int cnt = min(32, dmax - c * 32);
        int iters = (cnt + 1) >> 1;
#pragma unroll 2
        for (int j = 0; j < iters; j++) {
            int2 rec = lds[wave][h2][c & 1][j * 2 + epair][head];
            float w = __int_as_float(rec.y);
            float4 fv = fp[(size_t)rec.x * 16 + dp];
            __half2 p0 = *(__half2*)&fv.x, p1 = *(__half2*)&fv.y;
            __half2 p2 = *(__half2*)&fv.z, p3 = *(__half2*)&fv.w;
            a[0] = fmaf(__half2float(__low2half(p0)), w, a[0]);
            a[1] = fmaf(__half2float(__high2half(p0)), w, a[1]);
            a[2] = fmaf(__half2float(__low2half(p1)), w, a[2]);
            a[3] = fmaf(__half2float(__high2half(p1)), w, a[3]);
            a[4] = fmaf(__half2float(__low2half(p2)), w, a[4]);
            a[5] = fmaf(__half2float(__high2half(p2)), w, a[5]);
            a[6] = fmaf(__half2float(__low2half(p3)), w, a[6]);
            a[7] = fmaf(__half2float(__high2half(p3)), w, a[7]);
            s += w;
        }
    }
#pragma unroll
    for (int k = 0; k < 8; k++) a[k] += __shfl_xor(a[k], 16, 64);
    s += __shfl_xor(s, 16, 64);
    float r[8] = {};
    if (epair == 0) {
        float inv = 1.f / s;
        int d0 = dp * 8;
#pragma unroll
        for (int k = 0; k < 8; k++) r[k] = a[k] * inv;
        if (layer > 0) {
            float4 hraw = *reinterpret_cast<const float4*>(&h[(size_t)n * HDIM + d0]);
            __half2 q0 = *(__half2*)&hraw.x, q1 = *(__half2*)&hraw.y;
            __half2 q2 = *(__half2*)&hraw.z, q3 = *(__half2*)&hraw.w;
            float hv[8] = {__half2float(__low2half(q0)), __half2float(__high2half(q0)),
                           __half2float(__low2half(q1)), __half2float(__high2half(q1)),
                           __half2float(__low2half(q2)), __half2float(__high2half(q2)),
                           __half2float(__low2half(q3)), __half2float(__high2half(q3))};
            float4 sc0 = *reinterpret_cast<const float4*>(&s_sc[d0]);
            float4 sc1 = *reinterpret_cast<const float4*>(&s_sc[d0 + 4]);
            float4 sh0 = *reinterpret_cast<const float4*>(&s_sh[d0]);
            float4 sh1 = *reinterpret_cast<const float4*>(&s_sh[d0 + 4]);
            float scv[8] = {sc0.x, sc0.y, sc0.z, sc0.w, sc1.x, sc1.y, sc1.z, sc1.w};
            float shv[8] = {sh0.x, sh0.y, sh0.z, sh0.w, sh1.x, sh1.y, sh1.z, sh1.w};
#pragma unroll
            for (int k = 0; k < 8; k++) {
                float t = hv[k] * scv[k] + shv[k];
                t = (t > 0.f) ? t : expm1f(t);
                r[k] += t;
                r[k] = (r[k] > 0.f) ? r[k] : expm1f(r[k]);
            }
        }
        float sn = snorm_n[n];
#pragma unroll
        for (int k = 0; k < 8; k++) r[k] *= sn;
        float4 outv;
        *(__half2*)&outv.x = __floats2half2_rn(r[0], r[1]);
        *(__half2*)&outv.y = __floats2half2_rn(r[2], r[3]);
        *(__half2*)&outv.z = __floats2half2_rn(r[4], r[5]);
        *(__half2*)&outv.w = __floats2half2_rn(r[6], r[7]);
        *reinterpret_cast<float4*>(&h[(size_t)n * HDIM + d0]) = outv;
    }

    // ---- BN partials: per-block LDS reduce + one atomicAdd per (c,which); NO fences ----
    float* bsum = reinterpret_cast<float*>(lds);   // 2048 floats used (of 4096)
    __syncthreads();          // all waves done with their lds hot-loop regions
    if (epair == 0) {
        int n8 = wave * 2 + h2;
        int cbase = n8 * 128 + dp * 8;
#pragma unroll
        for (int k = 0; k < 8; k++) {
            bsum[cbase + k] = r[k];
            bsum[1024 + cbase + k] = r[k] * r[k];
        }
    }
    __syncthreads();
    {
        int c = tid & 127, which = tid >> 7;   // which: 0=sum, 1=sumsq
        float v = 0.f;
#pragma unroll
        for (int n8 = 0; n8 < 8; n8++) v += bsum[which * 1024 + n8 * 128 + c];
        atomicAdd(&bn_cur[(blockIdx.x & (BN_BUCKETS - 1)) * 256 + which * 128 + c], v);
    }
}

// ---------------- classifier (h fp16), BN finalize fused ----------------
__global__ void k_classifier(const __half* __restrict__ h, const float* __restrict__ W1,
                             const float* __restrict__ b1, const float* __restrict__ W2,
                             const float* __restrict__ b2, const float* __restrict__ bn_prev,
                             const float* __restrict__ gamma, const float* __restrict__ beta,
                             float* __restrict__ out) {
    __shared__ float hs[16][128];
    __shared__ __align__(16) float s_sc[128];
    __shared__ __align__(16) float s_sh[128];
    int tid = threadIdx.x;
    {
        float* red = &hs[0][0];   // alias; hs written after
        int c = tid & 127, which = tid >> 7;
        float t = 0.f;
#pragma unroll
        for (int b = 0; b < BN_BUCKETS; b++) t += bn_prev[b * 256 + which * 128 + c];
        red[tid] = t;
        __syncthreads();
        if (tid < 128) {
            float mu = red[tid] * (1.f / N_NODES);
            float var = red[128 + tid] * (1.f / N_NODES) - mu * mu;
            float sc = gamma[tid] * rsqrtf(var + 1e-5f);
            s_sc[tid] = sc;
            s_sh[tid] = beta[tid] - mu * sc;
        }
        __syncthreads();
    }
    int nbase = blockIdx.x * 16;
    for (int i = tid; i < 16 * 128; i += 256) {
        int r = i >> 7, c = i & 127;
        int n = nbase + r;
        float v = 0.f;
        if (n < N_NODES) {
            v = __half2float(h[(size_t)n * HDIM + c]) * s_sc[c] + s_sh[c];
            v = (v > 0.f) ? v : expm1f(v);
        }
        hs[r][c] = v;
    }
    __syncthreads();
    int j = tid & 63;
    int g = tid >> 6;
    float bj = b1[j];
    float acc[4] = {bj, bj, bj, bj};
    for (int k = 0; k < 128; k++) {
        float w = W1[k * 64 + j];
#pragma unroll
        for (int i = 0; i < 4; i++) acc[i] += hs[g * 4 + i][k] * w;
    }
    float w20 = W2[j * 2], w21 = W2[j * 2 + 1];
    float res[8];
#pragma unroll
    for (int i = 0; i < 4; i++) {
        float hid = fmaxf(acc[i], 0.f);
        res[2 * i] = hid * w20;
        res[2 * i + 1] = hid * w21;
    }
#pragma unroll
    for (int off = 1; off < 64; off <<= 1)
#pragma unroll
        for (int i = 0; i < 8; i++) res[i] += __shfl_xor(res[i], off, 64);
    if (j < 8) {
        int n = nbase + g * 4 + (j >> 1);
        if (n < N_NODES) out[n * 2 + (j & 1)] = res[j] + b2[j & 1];
    }
}

// ----------------------------------------------------------------
extern "C" void kernel_launch(void* const* d_in, const int* in_sizes, int n_in,
                              void* d_out, int out_size, void* d_ws, size_t ws_size,
                              hipStream_t stream) {
    const int* x = (const int*)d_in[0];
    const int* src = (const int*)d_in[1];
    const int* dst = (const int*)d_in[2];
    const float* snorm_n = (const float*)d_in[3];
    const float* embed = (const float*)d_in[5];
    const float* Ws[3] = {(const float*)d_in[6], (const float*)d_in[11], (const float*)d_in[16]};
    const float* als[3] = {(const float*)d_in[7], (const float*)d_in[12], (const float*)d_in[17]};
    const float* ars[3] = {(const float*)d_in[8], (const float*)d_in[13], (const float*)d_in[18]};
    const float* gms[3] = {(const float*)d_in[9], (const float*)d_in[14], (const float*)d_in[19]};
    const float* bts[3] = {(const float*)d_in[10], (const float*)d_in[15], (const float*)d_in[20]};
    const float* cls1_w = (const float*)d_in[21];
    const float* cls1_b = (const float*)d_in[22];
    const float* cls2_w = (const float*)d_in[23];
    const float* cls2_b = (const float*)d_in[24];
    float* out = (float*)d_out;

    char* ws = (char*)d_ws;
    size_t off = 0;
    auto alloc = [&](size_t bytes) {
        void* p = ws + off;
        off = (off + bytes + 255) & ~(size_t)255;
        return p;
    };
    __half* h = (__half*)alloc((size_t)N_NODES * HDIM * 2);
    __half* feat_h = (__half*)alloc((size_t)N_NODES * HDIM * 2);
    float* el = (float*)alloc((size_t)N_NODES * 4 * 4);
    float* er = (float*)alloc((size_t)N_NODES * 4 * 4);
    int* rowstart = (int*)alloc((size_t)(N_NODES + 1) * 4);
    int* esrc = (int*)alloc((size_t)N_EDGES * 4);
    int* g_cursor = (int*)alloc((size_t)NB2 * 4);
    float* bn_part = (float*)alloc((size_t)3 * BN_BUCKETS * 256 * 4);
    __half* wpkh = (__half*)alloc((size_t)3 * 16384 * 2);
    unsigned* g_bucket = (unsigned*)feat_h;  // 4 MB alias; CSR build finishes before gemm
    (void)ws_size; (void)in_sizes; (void)n_in; (void)out_size;

    k_wpack<<<(3 * 2048 + 255) / 256, 256, 0, stream>>>(Ws[0], Ws[1], Ws[2], wpkh,
                                                        bn_part, g_cursor);
    k_partA<<<GA, 1024, 0, stream>>>(src, dst, g_cursor, g_bucket);
    k_partB<<<NB2, 1024, 0, stream>>>(g_bucket, g_cursor, rowstart, esrc);

    for (int L = 0; L < 3; L++) {
        const f16x8* wB = reinterpret_cast<const f16x8*>(wpkh + ((size_t)L << 14));
        const float* bn_prev = bn_part + (size_t)(L == 0 ? 0 : L - 1) * BN_BUCKETS * 256;
        float* bn_cur = bn_part + (size_t)L * BN_BUCKETS * 256;
        int gprev = (L == 0) ? 0 : L - 1;
        k_gemm6<<<(N_NODES + 63) / 64, 256, 0, stream>>>(h, x, embed, wB, feat_h,
                                                         bn_prev, gms[gprev], bts[gprev],
                                                         als[L], ars[L], el, er, L == 0 ? 0 : 1);
        k_agg10<<<AGG_BLOCKS, 256, 0, stream>>>(feat_h, el, er, rowstart, esrc,
                                                snorm_n, h, bn_prev, gms[gprev], bts[gprev],
                                                bn_cur, L);
    }

    k_classifier<<<(N_NODES + 15) / 16, 256, 0, stream>>>(h, cls1_w, cls1_b, cls2_w, cls2_b,
                                                          bn_part + (size_t)2 * BN_BUCKETS * 256,
                                                          gms[2], bts[2], out);
}